// Round 6
// baseline (416.079 us; speedup 1.0000x reference)
//
#include <hip/hip_runtime.h>
#include <cstdint>
#include <cstddef>

// Problem constants: B=64, N=1024, D=512, C=512, K=16, GAMMA=0.3, TEMP=0.07
#define INV_TEMP 14.285714285714285714f
#define GAMMA_ 0.3f

// Old path rows: 0..65535 = vpat; 65536..65599 = cls; 65600..65663 = pad.
#define ROWS_PAD 65664
// New path rows: 0..65535 vpat; 65536..65599 cls; rest pad to 514*128.
#define ROWS_NEW 65792

typedef short short8 __attribute__((ext_vector_type(8)));
typedef float floatx4 __attribute__((ext_vector_type(4)));

#if __has_builtin(__builtin_amdgcn_fmed3f)
#define MED3(v, hi, lo) __builtin_amdgcn_fmed3f((v), (hi), (lo))
#else
#define MED3(v, hi, lo) fmaxf(fminf((v), (hi)), (lo))
#endif

__device__ __forceinline__ unsigned short f2bf(float x) {
  unsigned int u = __float_as_uint(x);
  u += 0x7FFFu + ((u >> 16) & 1u);  // round-to-nearest-even
  return (unsigned short)(u >> 16);
}
__device__ __forceinline__ float bf2f(unsigned short h) {
  return __uint_as_float(((unsigned int)h) << 16);
}

// Branchless sorted-descending top-16 insert: 15 med3 + 1 max, depth-1 ILP.
__device__ __forceinline__ void insert16(float (&top)[16], float v) {
#pragma unroll
  for (int j = 15; j >= 1; --j) top[j] = MED3(v, top[j - 1], top[j]);
  top[0] = fmaxf(top[0], v);
}

#define GL16(srcp, dstp)                                                        \
  __builtin_amdgcn_global_load_lds(                                             \
      (const __attribute__((address_space(1))) void*)(srcp),                    \
      (__attribute__((address_space(3))) void*)(dstp), 16, 0, 0)

// ===========================================================================
// NEW PATH
// ===========================================================================

// pack v3 (unchanged from r5): 4 rows/wave; lane owns 8 contiguous floats;
// 16B short8 stores. Unified row space: 0..511 text -> Bh/Bl; 512.. -> A row
// r-512 (vpat < 65536, cls < 65600, zeros to 65792).
__global__ __launch_bounds__(256) void pack_kernel(
    const float* __restrict__ vcls, const float* __restrict__ vpat,
    const float* __restrict__ text,
    unsigned short* __restrict__ Bh, unsigned short* __restrict__ Bl,
    unsigned short* __restrict__ Ah, unsigned short* __restrict__ Al) {
  const int g = blockIdx.x * 4 + (threadIdx.x >> 6);  // wave id 0..16575
  const int lane = threadIdx.x & 63;
  const int r0 = g * 4;

  const float* src = nullptr;
  size_t srow = 0;
  unsigned short *dh, *dl;
  bool iszero = false;
  if (r0 < 512) {
    src = text;
    srow = (size_t)r0;
    dh = Bh + (size_t)r0 * 512;
    dl = Bl + (size_t)r0 * 512;
  } else {
    const int r = r0 - 512;  // 0..65788
    dh = Ah + (size_t)r * 512;
    dl = Al + (size_t)r * 512;
    if (r < 65536) {
      src = vpat;
      srow = (size_t)r;
    } else if (r < 65600) {
      src = vcls;
      srow = (size_t)(r - 65536);
    } else {
      iszero = true;
    }
  }

  float4 v[4][2];
  if (iszero) {
    const float4 z = make_float4(0.f, 0.f, 0.f, 0.f);
#pragma unroll
    for (int q = 0; q < 4; ++q) { v[q][0] = z; v[q][1] = z; }
  } else {
#pragma unroll
    for (int q = 0; q < 4; ++q) {
      const float4* s4 = (const float4*)(src + (srow + q) * 512);
      v[q][0] = s4[2 * lane];
      v[q][1] = s4[2 * lane + 1];
    }
  }

  float ss[4];
#pragma unroll
  for (int q = 0; q < 4; ++q) {
    const float4 a = v[q][0], b = v[q][1];
    ss[q] = a.x * a.x + a.y * a.y + a.z * a.z + a.w * a.w +
            b.x * b.x + b.y * b.y + b.z * b.z + b.w * b.w;
  }
#pragma unroll
  for (int off = 32; off; off >>= 1) {
#pragma unroll
    for (int q = 0; q < 4; ++q) ss[q] += __shfl_xor(ss[q], off);
  }

#pragma unroll
  for (int q = 0; q < 4; ++q) {
    const float scale = 1.0f / fmaxf(sqrtf(ss[q]), 1e-12f);
    const float a[8] = {v[q][0].x * scale, v[q][0].y * scale,
                        v[q][0].z * scale, v[q][0].w * scale,
                        v[q][1].x * scale, v[q][1].y * scale,
                        v[q][1].z * scale, v[q][1].w * scale};
    short8 h, l;
#pragma unroll
    for (int e = 0; e < 8; ++e) {
      const unsigned short hb = f2bf(a[e]);
      h[e] = (short)hb;
      l[e] = (short)f2bf(a[e] - bf2f(hb));
    }
    *(short8*)(dh + (size_t)q * 512 + 8 * lane) = h;
    *(short8*)(dl + (size_t)q * 512 + 8 * lane) = l;
  }
}

// gemm v4 = r1/r5's verified 135us structure (128x128, 2x2 waves, single
// 32KB LDS, 2-barrier K-loop, chunk-XOR swizzle, 0 bank conflicts), with a
// TRANSPOSED epilogue: main rows write logitsT[b][c][n] (acc[i][j] holds 4
// consecutive n -> one aligned float4 store; 16 stores/thread vs 64 scalar).
// Across a wave the 4 kg-groups complete 64B lines per column. cls rows
// (bm>=512) go to clsbuf[b][c]. pstat unchanged (fixed-max-1.0 sumexp).
__global__ __launch_bounds__(256) void gemm_lean_kernel(
    const unsigned short* __restrict__ Ah, const unsigned short* __restrict__ Al,
    const unsigned short* __restrict__ Bh, const unsigned short* __restrict__ Bl,
    float* __restrict__ logitsT, float* __restrict__ clsbuf,
    float* __restrict__ pstat) {
  __shared__ __align__(16) unsigned short smem[16384];  // 32 KB
  unsigned short* sA = smem;         // [128][64] bf16, chunk-swizzled
  unsigned short* sB = smem + 8192;  // [128][64] bf16, chunk-swizzled
  const int tid = threadIdx.x;
  const int lane = tid & 63;
  const int w = tid >> 6;
  const int wm = w >> 1, wn = w & 1;

  const int L = blockIdx.x;                 // 0..2055
  const int wg = (L & 7) * 257 + (L >> 3);  // bijective (2056 = 8*257)
  const int bn = wg & 3;                    // 0..3
  const int bm = wg >> 2;                   // 0..513

  unsigned aOff[4], bOff[4];
#pragma unroll
  for (int q = 0; q < 4; ++q) {
    const int s = tid + q * 256;
    const int row = s >> 3, pos = s & 7;
    const int g = pos ^ (row & 7);
    aOff[q] = (unsigned)(bm * 128 + row) * 512u + (unsigned)g * 8u;  // ushort
    bOff[q] = (unsigned)(bn * 128 + row) * 512u + (unsigned)g * 8u;
  }

  const int l15 = lane & 15, kg = lane >> 4;
  int fA[4][2], fB[4][2];
#pragma unroll
  for (int i = 0; i < 4; ++i) {
    const int ml = wm * 64 + i * 16 + l15;
    const int nl = wn * 64 + i * 16 + l15;
#pragma unroll
    for (int k2 = 0; k2 < 2; ++k2) {
      const int c = k2 * 4 + kg;
      fA[i][k2] = ml * 64 + (c ^ (ml & 7)) * 8;
      fB[i][k2] = nl * 64 + (c ^ (nl & 7)) * 8;
    }
  }

  floatx4 acc[4][4] = {};

#pragma unroll 1
  for (int seg = 0; seg < 3; ++seg) {
    const unsigned short* Asrc = (seg == 1) ? Al : Ah;
    const unsigned short* Bsrc = (seg == 2) ? Bl : Bh;
#pragma unroll 1
    for (int t8 = 0; t8 < 8; ++t8) {
      const unsigned ko = (unsigned)t8 * 64u;
#pragma unroll
      for (int q = 0; q < 4; ++q)
        GL16(Asrc + aOff[q] + ko, sA + (w * 512 + q * 2048));
#pragma unroll
      for (int q = 0; q < 4; ++q)
        GL16(Bsrc + bOff[q] + ko, sB + (w * 512 + q * 2048));
      __syncthreads();
#pragma unroll
      for (int k2 = 0; k2 < 2; ++k2) {
        short8 a[4], b[4];
#pragma unroll
        for (int i = 0; i < 4; ++i) a[i] = *(const short8*)(sA + fA[i][k2]);
#pragma unroll
        for (int j = 0; j < 4; ++j) b[j] = *(const short8*)(sB + fB[j][k2]);
#pragma unroll
        for (int i = 0; i < 4; ++i)
#pragma unroll
          for (int j = 0; j < 4; ++j)
            acc[i][j] = __builtin_amdgcn_mfma_f32_16x16x32_bf16(
                a[i], b[j], acc[i][j], 0, 0, 0);
      }
      __syncthreads();
    }
  }

  // C/D layout: col=lane&15, row=(lane>>4)*4+reg  [m89/m91 verified]
  const unsigned rowb0 = (unsigned)(bm * 128 + wm * 64 + kg * 4);
  const unsigned colb0 = (unsigned)(bn * 128 + wn * 64 + l15);
  const int pk = bn * 2 + wn;  // pstat slot 0..7
  const bool isMain = (bm < 512);           // wave-uniform
  const unsigned b_blk = rowb0 >> 10;       // batch (main rows)
  const unsigned nbase = rowb0 & 1023;      // n offset within batch
#pragma unroll
  for (int i = 0; i < 4; ++i) {
#pragma unroll
    for (int j = 0; j < 4; ++j) {
      const unsigned col = colb0 + j * 16;
      if (isMain) {
        // 4 consecutive n (r=0..3) -> one aligned float4 store.
        *(floatx4*)(logitsT + ((size_t)(b_blk * 512 + col)) * 1024 +
                    (nbase + i * 16)) = acc[i][j];
      } else {
#pragma unroll
        for (int r = 0; r < 4; ++r) {
          const int br = (int)(rowb0 + i * 16 + r) - 65536;  // 0..255
          if (br < 64) clsbuf[br * 512 + col] = acc[i][j][r];
        }
      }
    }
#pragma unroll
    for (int r = 0; r < 4; ++r) {
      float se = __expf((acc[i][0][r] - 1.0f) * INV_TEMP) +
                 __expf((acc[i][1][r] - 1.0f) * INV_TEMP) +
                 __expf((acc[i][2][r] - 1.0f) * INV_TEMP) +
                 __expf((acc[i][3][r] - 1.0f) * INV_TEMP);
      se += __shfl_xor(se, 1);
      se += __shfl_xor(se, 2);
      se += __shfl_xor(se, 4);
      se += __shfl_xor(se, 8);
      if (l15 == 0) pstat[(size_t)(rowb0 + i * 16 + r) * 8 + pk] = se;
    }
  }
}

// Fused top-k over TRANSPOSED logits: 8 threads per (b,c) read the 4KB
// contiguous n-row as float4 chunks (128B contiguous per 8-lane group);
// per-thread top-16 over 128 n; LDS merge of 8 partials; finisher adds
// sum-exp + fused aff_g and writes out. sLW padded (idx r + r>>7) to break
// the stride-128 bank conflict; sTop padded to 17.
__global__ __launch_bounds__(256) void topk_fused_t_kernel(
    const float* __restrict__ LT, const float* __restrict__ clsbuf,
    const float* __restrict__ pstat, float* __restrict__ out) {
  const int b = blockIdx.x;     // 0..63
  const int cg = blockIdx.y;    // 0..15
  const int tid = threadIdx.x;  // 0..255
  const int cl = tid >> 3;      // 0..31
  const int nk = tid & 7;       // 0..7
  const int c = cg * 32 + cl;

  __shared__ float sLW[1032];        // padded: index r + (r>>7)
  __shared__ float sTop[32][7][17];  // padded inner dim

  // Phase A: LW[n] = -(ln(sum_k pstat[n][k]) + invT) for all 1024 n of b.
#pragma unroll
  for (int q = 0; q < 4; ++q) {
    const int r = tid * 4 + q;  // 0..1023
    const float* p = pstat + ((size_t)b * 1024 + r) * 8;
    float S = 0.f;
#pragma unroll
    for (int k = 0; k < 8; ++k) S += p[k];
    sLW[r + (r >> 7)] = -(__logf(S) + INV_TEMP);
  }
  __syncthreads();

  // Phase B: top-16 over this thread's 128 n-slice of column c.
  float top[16];
#pragma unroll
  for (int j = 0; j < 16; ++j) top[j] = -3.0e38f;
  const float4* P =
      (const float4*)(LT + ((size_t)(b * 512 + c)) * 1024 + (size_t)nk * 128);
  const int lwb = nk * 129;  // nk*128 + pad offset (r>>7 == nk on this slice)
#pragma unroll 1
  for (int m = 0; m < 32; m += 4) {
    float4 v[4];
#pragma unroll
    for (int u = 0; u < 4; ++u) v[u] = P[m + u];
#pragma unroll
    for (int u = 0; u < 4; ++u) {
      const int base = lwb + (m + u) * 4;
      insert16(top, fmaf(v[u].x, INV_TEMP, sLW[base + 0]));
      insert16(top, fmaf(v[u].y, INV_TEMP, sLW[base + 1]));
      insert16(top, fmaf(v[u].z, INV_TEMP, sLW[base + 2]));
      insert16(top, fmaf(v[u].w, INV_TEMP, sLW[base + 3]));
    }
  }

  // Phase C: merge 8 partials per column; finish.
  if (nk > 0) {
#pragma unroll
    for (int j = 0; j < 16; ++j) sTop[cl][nk - 1][j] = top[j];
  }
  __syncthreads();
  if (nk == 0) {
#pragma unroll
    for (int kb = 0; kb < 7; ++kb) {
      float v[16];
#pragma unroll
      for (int j = 0; j < 16; ++j) v[j] = sTop[cl][kb][j];
#pragma unroll
      for (int j = 0; j < 16; ++j) insert16(top, v[j]);
    }
    float se = 0.f;
#pragma unroll
    for (int j = 0; j < 16; ++j) se += __expf(top[j]);
    const float* pc = pstat + ((size_t)65536 + b) * 8;
    float S = 0.f;
#pragma unroll
    for (int k = 0; k < 8; ++k) S += pc[k];
    const float lg = clsbuf[b * 512 + c];
    const float ag = __expf(fmaf(lg, INV_TEMP, -(__logf(S) + INV_TEMP)));
    out[b * 512 + c] = GAMMA_ * ag + (1.0f - GAMMA_) * (se * (1.0f / 16.0f));
  }
}

// ===========================================================================
// OLD PATH (fallback if workspace too small) — r5's verified kernels.
// ===========================================================================

__global__ __launch_bounds__(256) void prep_kernel(
    const float* __restrict__ vcls, const float* __restrict__ text,
    unsigned short* __restrict__ Bh, unsigned short* __restrict__ Bl,
    float* __restrict__ Aext) {
  const int wid = blockIdx.x * 4 + (threadIdx.x >> 6);
  const int lane = threadIdx.x & 63;
  if (wid < 512) {
    const float* src = text + (size_t)wid * 512;
    const float4 v0 = ((const float4*)src)[lane];
    const float4 v1 = ((const float4*)src)[lane + 64];
    float ss = v0.x * v0.x + v0.y * v0.y + v0.z * v0.z + v0.w * v0.w +
               v1.x * v1.x + v1.y * v1.y + v1.z * v1.z + v1.w * v1.w;
#pragma unroll
    for (int off = 32; off; off >>= 1) ss += __shfl_xor(ss, off);
    const float scale = 1.0f / fmaxf(sqrtf(ss), 1e-12f);
    float a[8] = {v0.x * scale, v0.y * scale, v0.z * scale, v0.w * scale,
                  v1.x * scale, v1.y * scale, v1.z * scale, v1.w * scale};
    ushort4 h0, l0, h1, l1;
    h0.x = f2bf(a[0]); l0.x = f2bf(a[0] - bf2f(h0.x));
    h0.y = f2bf(a[1]); l0.y = f2bf(a[1] - bf2f(h0.y));
    h0.z = f2bf(a[2]); l0.z = f2bf(a[2] - bf2f(h0.z));
    h0.w = f2bf(a[3]); l0.w = f2bf(a[3] - bf2f(h0.w));
    h1.x = f2bf(a[4]); l1.x = f2bf(a[4] - bf2f(h1.x));
    h1.y = f2bf(a[5]); l1.y = f2bf(a[5] - bf2f(h1.y));
    h1.z = f2bf(a[6]); l1.z = f2bf(a[6] - bf2f(h1.z));
    h1.w = f2bf(a[7]); l1.w = f2bf(a[7] - bf2f(h1.w));
    ((ushort4*)(Bh + (size_t)wid * 512))[lane] = h0;
    ((ushort4*)(Bh + (size_t)wid * 512))[lane + 64] = h1;
    ((ushort4*)(Bl + (size_t)wid * 512))[lane] = l0;
    ((ushort4*)(Bl + (size_t)wid * 512))[lane + 64] = l1;
  } else {
    const int r = wid - 512;  // 0..127
    float4* dst = (float4*)(Aext + (size_t)r * 512);
    if (r < 64) {
      const float4* src = (const float4*)(vcls + (size_t)r * 512);
      dst[lane] = src[lane];
      dst[lane + 64] = src[lane + 64];
    } else {
      const float4 z = {0.f, 0.f, 0.f, 0.f};
      dst[lane] = z;
      dst[lane + 64] = z;
    }
  }
}

__global__ __launch_bounds__(256) void gemm_raw_kernel(
    const float* __restrict__ Apat, const float* __restrict__ Aext,
    const unsigned short* __restrict__ Bhi, const unsigned short* __restrict__ Blo,
    float* __restrict__ Cout, float* __restrict__ pstat) {
  __shared__ __align__(16) unsigned char smem[32768];
  float* sA = (float*)smem;
  unsigned short* sBh = (unsigned short*)(smem + 16384);
  unsigned short* sBl = (unsigned short*)(smem + 24576);
  const int tid = threadIdx.x;
  const int lane = tid & 63;
  const int w = tid >> 6;
  const int wm = w >> 1, wn = w & 1;

  const int L = blockIdx.x;  // 0..2051
  int bm, bn;
  if (L < 2048) {
    const int xcd = L & 7;
    const int slot = L >> 3;
    bn = slot & 3;
    bm = (slot >> 2) * 8 + xcd;
  } else {
    bm = 512;
    bn = L - 2048;
  }
  const float* Abase =
      (bm < 512) ? (Apat + (size_t)bm * 128 * 512) : Aext;

  unsigned aSrc[4];
#pragma unroll
  for (int q = 0; q < 4; ++q) {
    const int s = tid + q * 256;
    const int row = s >> 3, pos = s & 7;
    const int g = pos ^ (row & 7);
    aSrc[q] = (unsigned)row * 512u + (unsigned)g * 4u;
  }
  const int m0 = tid >> 2, g0 = (tid & 3) ^ ((m0 >> 1) & 3);
  const int i1 = 256 + tid;
  const int m1 = i1 >> 2, g1 = (i1 & 3) ^ ((m1 >> 1) & 3);
  const unsigned bO0 = (unsigned)(bn * 128 + m0) * 512u + (unsigned)g0 * 8u;
  const unsigned bO1 = (unsigned)(bn * 128 + m1) * 512u + (unsigned)g1 * 8u;

  const int l15 = lane & 15, kg = lane >> 4;
  int fA0[4], fA1[4], cB[4];
#pragma unroll
  for (int i = 0; i < 4; ++i) {
    const int ml = wm * 64 + i * 16 + l15;
    const int p0 = (2 * kg) ^ (ml & 7);
    const int p1 = (2 * kg + 1) ^ (ml & 7);
    fA0[i] = (ml * 8 + p0) * 4;
    fA1[i] = (ml * 8 + p1) * 4;
    const int nl = wn * 64 + i * 16 + l15;
    cB[i] = (nl * 4 + (kg ^ ((nl >> 1) & 3))) * 8;
  }

  floatx4 acc[4][4] = {};
  float ssq[4] = {0.f, 0.f, 0.f, 0.f};

  for (int ks = 0; ks < 16; ++ks) {
    const unsigned ko = (unsigned)ks * 32u;
#pragma unroll
    for (int q = 0; q < 4; ++q)
      GL16(Abase + aSrc[q] + ko, (unsigned short*)sA + (w * 512 + q * 2048));
    GL16(Bhi + bO0 + ko, sBh + (unsigned)tid * 8u);
    GL16(Bhi + bO1 + ko, sBh + 2048u + (unsigned)tid * 8u);
    GL16(Blo + bO0 + ko, sBl + (unsigned)tid * 8u);
    GL16(Blo + bO1 + ko, sBl + 2048u + (unsigned)tid * 8u);
    __syncthreads();

    short8 bh[4], bl[4];
#pragma unroll
    for (int j = 0; j < 4; ++j) {
      bh[j] = *(const short8*)(sBh + cB[j]);
      bl[j] = *(const short8*)(sBl + cB[j]);
    }
#pragma unroll
    for (int i = 0; i < 4; ++i) {
      const float4 x0 = *(const float4*)(sA + fA0[i]);
      const float4 x1 = *(const float4*)(sA + fA1[i]);
      const float xs[8] = {x0.x, x0.y, x0.z, x0.w, x1.x, x1.y, x1.z, x1.w};
      short8 ah, al;
#pragma unroll
      for (int e = 0; e < 8; ++e) {
        const float f = xs[e];
        ssq[i] = fmaf(f, f, ssq[i]);
        const unsigned u = __float_as_uint(f) + 0x8000u;
        ah[e] = (short)(u >> 16);
        const float hif = __uint_as_float(u & 0xFFFF0000u);
        al[e] = (short)(__float_as_uint(f - hif) >> 16);
      }
#pragma unroll
      for (int j = 0; j < 4; ++j) {
        acc[i][j] = __builtin_amdgcn_mfma_f32_16x16x32_bf16(ah, bh[j], acc[i][j], 0, 0, 0);
        acc[i][j] = __builtin_amdgcn_mfma_f32_16x16x32_bf16(ah, bl[j], acc[i][j], 0, 0, 0);
        acc[i][j] = __builtin_amdgcn_mfma_f32_16x16x32_bf16(al, bh[j], acc[i][j], 0, 0, 0);
      }
    }
    __syncthreads();
  }

  float inv[4];
#pragma unroll
  for (int i = 0; i < 4; ++i) {
    float s = ssq[i];
    s += __shfl_xor(s, 16);
    s += __shfl_xor(s, 32);
    inv[i] = 1.0f / fmaxf(sqrtf(s), 1e-12f);
  }

  const int quad = kg;
  const unsigned rowb0 = (unsigned)(bm * 128 + wm * 64 + quad * 4);
  const unsigned colb0 = (unsigned)(bn * 128 + wn * 64 + l15);
  const int pk = bn * 2 + wn;
#pragma unroll
  for (int i = 0; i < 4; ++i) {
    float iv[4];
#pragma unroll
    for (int r = 0; r < 4; ++r) iv[r] = __shfl(inv[i], quad * 20 + r);
    float sc[4][4];
#pragma unroll
    for (int j = 0; j < 4; ++j)
#pragma unroll
      for (int r = 0; r < 4; ++r) sc[j][r] = acc[i][j][r] * iv[r];
#pragma unroll
    for (int j = 0; j < 4; ++j) {
      const unsigned col = colb0 + j * 16;
#pragma unroll
      for (int r = 0; r < 4; ++r)
        Cout[(size_t)(rowb0 + i * 16 + r) * 512 + col] = sc[j][r];
    }
#pragma unroll
    for (int r = 0; r < 4; ++r) {
      float se = __expf((sc[0][r] - 1.0f) * INV_TEMP) +
                 __expf((sc[1][r] - 1.0f) * INV_TEMP) +
                 __expf((sc[2][r] - 1.0f) * INV_TEMP) +
                 __expf((sc[3][r] - 1.0f) * INV_TEMP);
      se += __shfl_xor(se, 1);
      se += __shfl_xor(se, 2);
      se += __shfl_xor(se, 4);
      se += __shfl_xor(se, 8);
      if (l15 == 0) pstat[(size_t)(rowb0 + i * 16 + r) * 8 + pk] = se;
    }
  }
}

// r5's row-major fused topk (fallback path only).
__global__ __launch_bounds__(256) void topk_fused_kernel(
    const float* __restrict__ L, const float* __restrict__ pstat,
    float* __restrict__ out) {
  const int b = blockIdx.x;
  const int cg = blockIdx.y;
  const int tid = threadIdx.x;
  const int rq = tid >> 6;
  const int cl = tid & 63;
  const int c = cg * 64 + cl;

  __shared__ float sLW[1024];
  __shared__ float sTop[3][64][16];

#pragma unroll
  for (int q = 0; q < 4; ++q) {
    const int r = tid * 4 + q;
    const float* p = pstat + ((size_t)b * 1024 + r) * 8;
    float S = 0.f;
#pragma unroll
    for (int k = 0; k < 8; ++k) S += p[k];
    sLW[r] = -(__logf(S) + INV_TEMP);
  }
  __syncthreads();

  float top[16];
#pragma unroll
  for (int j = 0; j < 16; ++j) top[j] = -3.0e38f;
  const float* Lp = L + ((size_t)b * 1024 + (size_t)rq * 256) * 512 + c;
  const int lwb = rq * 256;
#pragma unroll 1
  for (int n0 = 0; n0 < 256; n0 += 8) {
    float v[8];
#pragma unroll
    for (int u = 0; u < 8; ++u) v[u] = Lp[(size_t)(n0 + u) * 512];
#pragma unroll
    for (int u = 0; u < 8; ++u)
      insert16(top, fmaf(v[u], INV_TEMP, sLW[lwb + n0 + u]));
  }

  if (rq > 0) {
#pragma unroll
    for (int j = 0; j < 16; ++j) sTop[rq - 1][cl][j] = top[j];
  }
  __syncthreads();
  if (rq == 0) {
#pragma unroll
    for (int kb = 0; kb < 3; ++kb) {
      float v[16];
#pragma unroll
      for (int j = 0; j < 16; ++j) v[j] = sTop[kb][cl][j];
#pragma unroll
      for (int j = 0; j < 16; ++j) insert16(top, v[j]);
    }
    float se = 0.f;
#pragma unroll
    for (int j = 0; j < 16; ++j) se += __expf(top[j]);
    const float* pc = pstat + ((size_t)65536 + b) * 8;
    float S = 0.f;
#pragma unroll
    for (int k = 0; k < 8; ++k) S += pc[k];
    const float lg = L[((size_t)65536 + b) * 512 + c];
    const float ag = __expf(fmaf(lg, INV_TEMP, -(__logf(S) + INV_TEMP)));
    out[b * 512 + c] = GAMMA_ * ag + (1.0f - GAMMA_) * (se * (1.0f / 16.0f));
  }
}

// ---------------------------------------------------------------------------
extern "C" void kernel_launch(void* const* d_in, const int* in_sizes, int n_in,
                              void* d_out, int out_size, void* d_ws, size_t ws_size,
                              hipStream_t stream) {
  const float* vcls = (const float*)d_in[0];  // [64,512]
  const float* vpat = (const float*)d_in[1];  // [64,1024,512]
  const float* text = (const float*)d_in[2];  // [512,512]
  float* out = (float*)d_out;                 // [64,512]

  char* p = (char*)d_ws;
  auto carve = [&](size_t bytes) -> char* {
    char* r = p;
    p += (bytes + 255) & ~(size_t)255;
    return r;
  };

  // ---- New path (pack v3 + r1 GEMM w/ transposed epilogue + contiguous
  // topk): ~272 MB workspace.
  {
    float* logitsT = (float*)carve((size_t)64 * 512 * 1024 * 4);  // [b][c][n]
    float* clsbuf = (float*)carve((size_t)64 * 512 * 4);
    unsigned short* Bh = (unsigned short*)carve((size_t)512 * 512 * 2);
    unsigned short* Bl = (unsigned short*)carve((size_t)512 * 512 * 2);
    float* pstat = (float*)carve((size_t)ROWS_NEW * 8 * 4);
    unsigned short* Ah = (unsigned short*)carve((size_t)ROWS_NEW * 512 * 2);
    unsigned short* Al = (unsigned short*)carve((size_t)ROWS_NEW * 512 * 2);
    if ((size_t)(p - (char*)d_ws) <= ws_size) {
      pack_kernel<<<4144, 256, 0, stream>>>(vcls, vpat, text, Bh, Bl, Ah, Al);
      gemm_lean_kernel<<<2056, 256, 0, stream>>>(Ah, Al, Bh, Bl, logitsT,
                                                 clsbuf, pstat);
      topk_fused_t_kernel<<<dim3(64, 16), 256, 0, stream>>>(logitsT, clsbuf,
                                                            pstat, out);
      return;
    }
  }

  // ---- Fallback: raw-A pipeline (~138 MB workspace), row-major fused topk.
  p = (char*)d_ws;
  float* logits = (float*)carve((size_t)ROWS_PAD * 512 * 4);
  unsigned short* Bh = (unsigned short*)carve((size_t)512 * 512 * 2);
  unsigned short* Bl = (unsigned short*)carve((size_t)512 * 512 * 2);
  float* pstat = (float*)carve((size_t)ROWS_PAD * 8 * 4);
  float* Aext = (float*)carve((size_t)128 * 512 * 4);
  if ((size_t)(p - (char*)d_ws) > ws_size) return;

  prep_kernel<<<160, 256, 0, stream>>>(vcls, text, Bh, Bl, Aext);
  gemm_raw_kernel<<<2052, 256, 0, stream>>>(vpat, Aext, Bh, Bl, logits, pstat);
  topk_fused_kernel<<<dim3(64, 8), 256, 0, stream>>>(logits, pstat, out);
}

// Round 7
// 355.311 us; speedup vs baseline: 1.1710x; 1.1710x over previous
//
#include <hip/hip_runtime.h>
#include <cstdint>
#include <cstddef>

// Problem constants: B=64, N=1024, D=512, C=512, K=16, GAMMA=0.3, TEMP=0.07
#define INV_TEMP 14.285714285714285714f
#define GAMMA_ 0.3f

// Rows: 0..65535 = vpat (b*1024+n); 65536..65599 = cls; 65600..65663 = pad.
#define ROWS_PAD 65664

typedef short short8 __attribute__((ext_vector_type(8)));
typedef short short4v __attribute__((ext_vector_type(4)));
typedef float floatx4 __attribute__((ext_vector_type(4)));

#if __has_builtin(__builtin_amdgcn_fmed3f)
#define MED3(v, hi, lo) __builtin_amdgcn_fmed3f((v), (hi), (lo))
#else
#define MED3(v, hi, lo) fmaxf(fminf((v), (hi)), (lo))
#endif

__device__ __forceinline__ unsigned short f2bf(float x) {
  unsigned int u = __float_as_uint(x);
  u += 0x7FFFu + ((u >> 16) & 1u);  // round-to-nearest-even
  return (unsigned short)(u >> 16);
}
__device__ __forceinline__ float bf2f(unsigned short h) {
  return __uint_as_float(((unsigned int)h) << 16);
}

// Branchless sorted-descending top-16 insert: 15 med3 + 1 max, depth-1 ILP.
__device__ __forceinline__ void insert16(float (&top)[16], float v) {
#pragma unroll
  for (int j = 15; j >= 1; --j) top[j] = MED3(v, top[j - 1], top[j]);
  top[0] = fmaxf(top[0], v);
}

#define GL16(srcp, dstp)                                                        \
  __builtin_amdgcn_global_load_lds(                                             \
      (const __attribute__((address_space(1))) void*)(srcp),                    \
      (__attribute__((address_space(3))) void*)(dstp), 16, 0, 0)

// ---------------------------------------------------------------------------
// Prep (r0 verified): wave-per-row. wid<512: text row -> l2norm + RNE bf16
// hi/lo (B matrix). wid 512..639: Aext row (cls raw fp32 copy rows 0..63;
// zeros 64..127). A-row norms are derived inside the GEMM.
__global__ __launch_bounds__(256) void prep_kernel(
    const float* __restrict__ vcls, const float* __restrict__ text,
    unsigned short* __restrict__ Bh, unsigned short* __restrict__ Bl,
    float* __restrict__ Aext) {
  const int wid = blockIdx.x * 4 + (threadIdx.x >> 6);
  const int lane = threadIdx.x & 63;
  if (wid < 512) {
    const float* src = text + (size_t)wid * 512;
    const float4 v0 = ((const float4*)src)[lane];
    const float4 v1 = ((const float4*)src)[lane + 64];
    float ss = v0.x * v0.x + v0.y * v0.y + v0.z * v0.z + v0.w * v0.w +
               v1.x * v1.x + v1.y * v1.y + v1.z * v1.z + v1.w * v1.w;
#pragma unroll
    for (int off = 32; off; off >>= 1) ss += __shfl_xor(ss, off);
    const float scale = 1.0f / fmaxf(sqrtf(ss), 1e-12f);
    float a[8] = {v0.x * scale, v0.y * scale, v0.z * scale, v0.w * scale,
                  v1.x * scale, v1.y * scale, v1.z * scale, v1.w * scale};
    ushort4 h0, l0, h1, l1;
    h0.x = f2bf(a[0]); l0.x = f2bf(a[0] - bf2f(h0.x));
    h0.y = f2bf(a[1]); l0.y = f2bf(a[1] - bf2f(h0.y));
    h0.z = f2bf(a[2]); l0.z = f2bf(a[2] - bf2f(h0.z));
    h0.w = f2bf(a[3]); l0.w = f2bf(a[3] - bf2f(h0.w));
    h1.x = f2bf(a[4]); l1.x = f2bf(a[4] - bf2f(h1.x));
    h1.y = f2bf(a[5]); l1.y = f2bf(a[5] - bf2f(h1.y));
    h1.z = f2bf(a[6]); l1.z = f2bf(a[6] - bf2f(h1.z));
    h1.w = f2bf(a[7]); l1.w = f2bf(a[7] - bf2f(h1.w));
    ((ushort4*)(Bh + (size_t)wid * 512))[lane] = h0;
    ((ushort4*)(Bh + (size_t)wid * 512))[lane + 64] = h1;
    ((ushort4*)(Bl + (size_t)wid * 512))[lane] = l0;
    ((ushort4*)(Bl + (size_t)wid * 512))[lane + 64] = l1;
  } else {
    const int r = wid - 512;  // 0..127
    float4* dst = (float4*)(Aext + (size_t)r * 512);
    if (r < 64) {
      const float4* src = (const float4*)(vcls + (size_t)r * 512);
      dst[lane] = src[lane];
      dst[lane + 64] = src[lane + 64];
    } else {
      const float4 z = {0.f, 0.f, 0.f, 0.f};
      dst[lane] = z;
      dst[lane + 64] = z;
    }
  }
}

// ---------------------------------------------------------------------------
// Raw-A split-bf16 GEMM v2: convert-once-in-LDS.
// r0's kernel converted each A element 4x in registers (VALUBusy 39% >
// MfmaUtil 19.5%). Now: after staging the fp32 A-tile, each thread converts
// its OWN 4 staged 16B slots IN PLACE (fp32 x4 -> [hi x4 | lo x4]); one extra
// barrier publishes the converted tile; A fragments become 4x ds_read_b64.
// Conversion work: 16 elem/thread/k-tile vs 64 (4x less VALU).
// Row norms: ssq accumulated per-slot during conversion (each thread's slot
// chunk g covers k = {32*ks + 4g..+3} over all ks; the 8 lanes owning row r's
// 8 chunks are lane-group (tid>>3) -> shfl_xor(1,2,4) reduce; inv published
// in a 512B LDS table aliased onto sBh (dead after the k-loop).
// Everything else (staging swizzles, B fragments, epilogue, pstat) = r0.
__global__ __launch_bounds__(256) void gemm_raw_kernel(
    const float* __restrict__ Apat, const float* __restrict__ Aext,
    const unsigned short* __restrict__ Bhi, const unsigned short* __restrict__ Blo,
    float* __restrict__ Cout, float* __restrict__ pstat) {
  __shared__ __align__(16) unsigned char smem[32768];
  // [0,16K): A tile, 128x32 fp32 staged; converted in place to hi|lo per slot.
  // [16K,24K): sBh. [24K,32K): sBl. sInv (512 B) aliases 16K after k-loop.
  unsigned short* sBh = (unsigned short*)(smem + 16384);
  unsigned short* sBl = (unsigned short*)(smem + 24576);
  const int tid = threadIdx.x;
  const int lane = tid & 63;
  const int w = tid >> 6;
  const int wm = w >> 1, wn = w & 1;

  const int L = blockIdx.x;  // 0..2051
  int bm, bn;
  if (L < 2048) {
    const int xcd = L & 7;
    const int slot = L >> 3;
    bn = slot & 3;
    bm = (slot >> 2) * 8 + xcd;
  } else {
    bm = 512;
    bn = L - 2048;
  }
  const float* Abase =
      (bm < 512) ? (Apat + (size_t)bm * 128 * 512) : Aext;

  // A staging: 1024 16B-slots; thread owns slots tid + q*256.
  // slot s -> row = s>>3, pos = s&7, source chunk g = pos ^ (row&7).
  unsigned aSrc[4];
#pragma unroll
  for (int q = 0; q < 4; ++q) {
    const int s = tid + q * 256;
    const int row = s >> 3, pos = s & 7;
    const int g = pos ^ (row & 7);
    aSrc[q] = (unsigned)row * 512u + (unsigned)g * 4u;  // float offset
  }
  // B staging: as r0 (4 chunks/row, pos = g ^ ((row>>1)&3)).
  const int m0 = tid >> 2, g0 = (tid & 3) ^ ((m0 >> 1) & 3);
  const int i1 = 256 + tid;
  const int m1 = i1 >> 2, g1 = (i1 & 3) ^ ((m1 >> 1) & 3);
  const unsigned bO0 = (unsigned)(bn * 128 + m0) * 512u + (unsigned)g0 * 8u;
  const unsigned bO1 = (unsigned)(bn * 128 + m1) * 512u + (unsigned)g1 * 8u;

  const int l15 = lane & 15, kg = lane >> 4;
  // A frag slot bases (bytes): chunks p0 = (2kg)^(ml&7), p1 = p0^1-ish.
  int fA0[4], fA1[4], cB[4];
#pragma unroll
  for (int i = 0; i < 4; ++i) {
    const int ml = wm * 64 + i * 16 + l15;
    const int p0 = (2 * kg) ^ (ml & 7);
    const int p1 = (2 * kg + 1) ^ (ml & 7);
    fA0[i] = (ml * 8 + p0) * 16;  // byte offset of slot
    fA1[i] = (ml * 8 + p1) * 16;
    const int nl = wn * 64 + i * 16 + l15;
    cB[i] = (nl * 4 + (kg ^ ((nl >> 1) & 3))) * 8;  // ushort index
  }

  floatx4 acc[4][4] = {};
  float ssqp[4] = {0.f, 0.f, 0.f, 0.f};  // per owned slot-row partials

#pragma unroll 1
  for (int ks = 0; ks < 16; ++ks) {
    const unsigned ko = (unsigned)ks * 32u;  // 32 elements
#pragma unroll
    for (int q = 0; q < 4; ++q)
      GL16(Abase + aSrc[q] + ko, (unsigned short*)smem + (w * 512 + q * 2048));
    GL16(Bhi + bO0 + ko, sBh + (unsigned)tid * 8u);
    GL16(Bhi + bO1 + ko, sBh + 2048u + (unsigned)tid * 8u);
    GL16(Blo + bO0 + ko, sBl + (unsigned)tid * 8u);
    GL16(Blo + bO1 + ko, sBl + 2048u + (unsigned)tid * 8u);
    __syncthreads();  // (a) tile staged

    // Convert own slots in place: fp32 x4 -> [hi x4 | lo x4] (same 16 B).
    // Disjoint slot ownership -> no cross-thread hazard before barrier (b).
#pragma unroll
    for (int q = 0; q < 4; ++q) {
      const int s = tid + q * 256;
      const float4 x = *(const float4*)(smem + s * 16);
      const float xs[4] = {x.x, x.y, x.z, x.w};
      unsigned hp[4], lp[4];
#pragma unroll
      for (int e = 0; e < 4; ++e) {
        const float f = xs[e];
        ssqp[q] = fmaf(f, f, ssqp[q]);
        const unsigned u = __float_as_uint(f) + 0x8000u;  // round-half-away
        hp[e] = u >> 16;
        const float hif = __uint_as_float(u & 0xFFFF0000u);
        lp[e] = __float_as_uint(f - hif) >> 16;  // exact resid, trunc
      }
      uint4 o;
      o.x = hp[0] | (hp[1] << 16);
      o.y = hp[2] | (hp[3] << 16);
      o.z = lp[0] | (lp[1] << 16);
      o.w = lp[2] | (lp[3] << 16);
      *(uint4*)(smem + s * 16) = o;
    }
    __syncthreads();  // (b) converted tile visible

    short8 bh[4], bl[4];
#pragma unroll
    for (int j = 0; j < 4; ++j) {
      bh[j] = *(const short8*)(sBh + cB[j]);
      bl[j] = *(const short8*)(sBl + cB[j]);
    }
#pragma unroll
    for (int i = 0; i < 4; ++i) {
      const short4v h0 = *(const short4v*)(smem + fA0[i]);
      const short4v l0 = *(const short4v*)(smem + fA0[i] + 8);
      const short4v h1 = *(const short4v*)(smem + fA1[i]);
      const short4v l1 = *(const short4v*)(smem + fA1[i] + 8);
      short8 ah, al;
      ah[0] = h0[0]; ah[1] = h0[1]; ah[2] = h0[2]; ah[3] = h0[3];
      ah[4] = h1[0]; ah[5] = h1[1]; ah[6] = h1[2]; ah[7] = h1[3];
      al[0] = l0[0]; al[1] = l0[1]; al[2] = l0[2]; al[3] = l0[3];
      al[4] = l1[0]; al[5] = l1[1]; al[6] = l1[2]; al[7] = l1[3];
#pragma unroll
      for (int j = 0; j < 4; ++j) {
        acc[i][j] = __builtin_amdgcn_mfma_f32_16x16x32_bf16(ah, bh[j], acc[i][j], 0, 0, 0);
        acc[i][j] = __builtin_amdgcn_mfma_f32_16x16x32_bf16(ah, bl[j], acc[i][j], 0, 0, 0);
        acc[i][j] = __builtin_amdgcn_mfma_f32_16x16x32_bf16(al, bh[j], acc[i][j], 0, 0, 0);
      }
    }
    __syncthreads();  // (c) frag reads done; next stage may overwrite
  }

  // Row inverse norms: ssqp[q] is row (tid>>3)+q*32's partial over chunk g.
  // The 8 owners of a row are lane-group (tid>>3): shfl_xor 1,2,4 sums them.
#pragma unroll
  for (int q = 0; q < 4; ++q) {
    float s = ssqp[q];
    s += __shfl_xor(s, 1);
    s += __shfl_xor(s, 2);
    s += __shfl_xor(s, 4);
    ssqp[q] = s;
  }
  float* sInv = (float*)(smem + 16384);  // aliases sBh (dead)
  if ((tid & 7) == 0) {
#pragma unroll
    for (int q = 0; q < 4; ++q)
      sInv[(tid >> 3) + q * 32] = 1.0f / fmaxf(sqrtf(ssqp[q]), 1e-12f);
  }
  __syncthreads();

  // C/D layout: col=lane&15, row=(lane>>4)*4+reg  [m89/m91 verified]
  const int quad = kg;
  const unsigned rowb0 = (unsigned)(bm * 128 + wm * 64 + quad * 4);
  const unsigned colb0 = (unsigned)(bn * 128 + wn * 64 + l15);
  const int pk = bn * 2 + wn;  // pstat slot 0..7
#pragma unroll
  for (int i = 0; i < 4; ++i) {
    float iv[4];
#pragma unroll
    for (int r = 0; r < 4; ++r)
      iv[r] = sInv[wm * 64 + i * 16 + quad * 4 + r];
    float sc[4][4];
#pragma unroll
    for (int j = 0; j < 4; ++j)
#pragma unroll
      for (int r = 0; r < 4; ++r) sc[j][r] = acc[i][j][r] * iv[r];
#pragma unroll
    for (int j = 0; j < 4; ++j) {
      const unsigned col = colb0 + j * 16;
#pragma unroll
      for (int r = 0; r < 4; ++r)
        Cout[(size_t)(rowb0 + i * 16 + r) * 512 + col] = sc[j][r];
    }
    // Fused partial sumexp (fixed max 1.0), reduce over l15 bits (cols).
#pragma unroll
    for (int r = 0; r < 4; ++r) {
      float se = __expf((sc[0][r] - 1.0f) * INV_TEMP) +
                 __expf((sc[1][r] - 1.0f) * INV_TEMP) +
                 __expf((sc[2][r] - 1.0f) * INV_TEMP) +
                 __expf((sc[3][r] - 1.0f) * INV_TEMP);
      se += __shfl_xor(se, 1);
      se += __shfl_xor(se, 2);
      se += __shfl_xor(se, 4);
      se += __shfl_xor(se, 8);
      if (l15 == 0) pstat[(size_t)(rowb0 + i * 16 + r) * 8 + pk] = se;
    }
  }
}

// ---------------------------------------------------------------------------
// Fused top-k (r5 verified): block = (b, 64-col group); 256 thr as 4
// row-quarters x 64 cols; s = l*invT + LW[n]; per-col 4-way LDS merge;
// rq==0 finishes (sum-exp of top-16, fused aff_g) and writes out.
__global__ __launch_bounds__(256) void topk_fused_kernel(
    const float* __restrict__ L, const float* __restrict__ pstat,
    float* __restrict__ out) {
  const int b = blockIdx.x;    // 0..63
  const int cg = blockIdx.y;   // 0..7
  const int tid = threadIdx.x; // 0..255
  const int rq = tid >> 6;     // row-quarter 0..3
  const int cl = tid & 63;
  const int c = cg * 64 + cl;

  __shared__ float sLW[1024];
  __shared__ float sTop[3][64][16];

#pragma unroll
  for (int q = 0; q < 4; ++q) {
    const int r = tid * 4 + q;  // 0..1023
    const float* p = pstat + ((size_t)b * 1024 + r) * 8;
    float S = 0.f;
#pragma unroll
    for (int k = 0; k < 8; ++k) S += p[k];
    sLW[r] = -(__logf(S) + INV_TEMP);
  }
  __syncthreads();

  float top[16];
#pragma unroll
  for (int j = 0; j < 16; ++j) top[j] = -3.0e38f;
  const float* Lp = L + ((size_t)b * 1024 + (size_t)rq * 256) * 512 + c;
  const int lwb = rq * 256;
#pragma unroll 1
  for (int n0 = 0; n0 < 256; n0 += 8) {
    float v[8];
#pragma unroll
    for (int u = 0; u < 8; ++u) v[u] = Lp[(size_t)(n0 + u) * 512];
#pragma unroll
    for (int u = 0; u < 8; ++u)
      insert16(top, fmaf(v[u], INV_TEMP, sLW[lwb + n0 + u]));
  }

  if (rq > 0) {
#pragma unroll
    for (int j = 0; j < 16; ++j) sTop[rq - 1][cl][j] = top[j];
  }
  __syncthreads();
  if (rq == 0) {
#pragma unroll
    for (int kb = 0; kb < 3; ++kb) {
      float v[16];
#pragma unroll
      for (int j = 0; j < 16; ++j) v[j] = sTop[kb][cl][j];
#pragma unroll
      for (int j = 0; j < 16; ++j) insert16(top, v[j]);
    }
    float se = 0.f;
#pragma unroll
    for (int j = 0; j < 16; ++j) se += __expf(top[j]);
    const float* pc = pstat + ((size_t)65536 + b) * 8;
    float S = 0.f;
#pragma unroll
    for (int k = 0; k < 8; ++k) S += pc[k];
    const float lg = L[((size_t)65536 + b) * 512 + c];
    const float ag = __expf(fmaf(lg, INV_TEMP, -(__logf(S) + INV_TEMP)));
    out[b * 512 + c] = GAMMA_ * ag + (1.0f - GAMMA_) * (se * (1.0f / 16.0f));
  }
}

// ---------------------------------------------------------------------------
extern "C" void kernel_launch(void* const* d_in, const int* in_sizes, int n_in,
                              void* d_out, int out_size, void* d_ws, size_t ws_size,
                              hipStream_t stream) {
  const float* vcls = (const float*)d_in[0];  // [64,512]
  const float* vpat = (const float*)d_in[1];  // [64,1024,512]
  const float* text = (const float*)d_in[2];  // [512,512]
  float* out = (float*)d_out;                 // [64,512]

  char* p = (char*)d_ws;
  auto carve = [&](size_t bytes) -> char* {
    char* r = p;
    p += (bytes + 255) & ~(size_t)255;
    return r;
  };
  // Minimal-footprint pipeline (~138 MB): raw-A gemm, no packed-A buffers.
  float* logits = (float*)carve((size_t)ROWS_PAD * 512 * 4);
  unsigned short* Bh = (unsigned short*)carve((size_t)512 * 512 * 2);
  unsigned short* Bl = (unsigned short*)carve((size_t)512 * 512 * 2);
  float* pstat = (float*)carve((size_t)ROWS_PAD * 8 * 4);
  float* Aext = (float*)carve((size_t)128 * 512 * 4);
  if ((size_t)(p - (char*)d_ws) > ws_size) return;

  prep_kernel<<<160, 256, 0, stream>>>(vcls, text, Bh, Bl, Aext);
  gemm_raw_kernel<<<2052, 256, 0, stream>>>(vpat, Aext, Bh, Bl, logits, pstat);
  topk_fused_kernel<<<dim3(64, 8), 256, 0, stream>>>(logits, pstat, out);
}